// Round 1
// baseline (554.929 us; speedup 1.0000x reference)
//
#include <hip/hip_runtime.h>

#define NQ 6
#define DDIM 64
#define FNUM 4
#define LNUM 2
#define OH 31
#define NGATES (FNUM * LNUM * NQ)   // 48

// ---------------------------------------------------------------------------
// Tiny prep kernel: compute the 48 2x2 complex rotation matrices once.
// Layout per gate: [U00r,U00i, U01r,U01i, U10r,U10i, U11r,U11i]
// ---------------------------------------------------------------------------
__global__ void prep_gates(const float* __restrict__ w, float* __restrict__ g) {
    int tid = threadIdx.x;
    if (tid >= NGATES) return;
    const float* p = w + tid * 3;
    float phi = p[0], theta = p[1], omega = p[2];
    float c, s;
    sincosf(0.5f * theta, &s, &c);
    float sapo, capo, samo, camo;
    sincosf(0.5f * (phi + omega), &sapo, &capo);
    sincosf(0.5f * (phi - omega), &samo, &camo);
    float* o = g + tid * 8;
    o[0] =  capo * c;  o[1] = -sapo * c;   // U00 = exp(-i(phi+omega)/2) c
    o[2] = -camo * s;  o[3] = -samo * s;   // U01 = -exp(i(phi-omega)/2) s
    o[4] =  camo * s;  o[5] = -samo * s;   // U10 = exp(-i(phi-omega)/2) s
    o[6] =  capo * c;  o[7] =  sapo * c;   // U11 = exp(i(phi+omega)/2) c
}

// ---------------------------------------------------------------------------
// Main kernel: one wave per patch; lane = amplitude index (c*16+kh*4+kw).
// ---------------------------------------------------------------------------
__global__ __launch_bounds__(256) void qconv_kernel(
        const float* __restrict__ x,
        const float* __restrict__ g,
        float* __restrict__ out) {
    __shared__ float gs[NGATES * 8];   // 384 floats = 1.5 KB
    for (int t = threadIdx.x; t < NGATES * 8; t += 256) gs[t] = g[t];
    __syncthreads();

    const int lane = threadIdx.x & 63;
    const int wid  = threadIdx.x >> 6;
    const int n    = blockIdx.x * 4 + wid;            // patch index, exact grid

    const int b   = n / (OH * OH);
    const int pos = n - b * (OH * OH);
    const int i   = pos / OH;
    const int j   = pos - i * OH;

    // patch element: lane = c*16 + kh*4 + kw
    const int c  = lane >> 4;
    const int kh = (lane >> 2) & 3;
    const int kw = lane & 3;
    const float v = x[(((b * 4 + c) * 64) + (i * 2 + kh)) * 64 + (j * 2 + kw)];

    // wave-allreduce of squared norm
    float ss = v * v;
#pragma unroll
    for (int m = 32; m >= 1; m >>= 1) ss += __shfl_xor(ss, m);
    const float psi0 = v * rsqrtf(ss);

    // Composed CNOT-layer permutations (source lane for new[d] = old[src]).
    // Layer l applies CNOT(w, (w+r)%6) for w=0..5 in order, r = l%5+1.
    // new[d] = old[sigma_0(sigma_1(...sigma_5(d)))] -> apply sigma_5 first.
    int src0 = lane, src1 = lane;
#pragma unroll
    for (int w = 5; w >= 0; --w) {
        int tq = (w + 1) % 6;
        src0 ^= ((src0 >> (5 - w)) & 1) << (5 - tq);
    }
#pragma unroll
    for (int w = 5; w >= 0; --w) {
        int tq = (w + 2) % 6;
        src1 ^= ((src1 >> (5 - w)) & 1) << (5 - tq);
    }

    for (int f = 0; f < FNUM; ++f) {
        float ar = psi0, ai = 0.0f;
#pragma unroll
        for (int rep = 0; rep < 2; ++rep) {
#pragma unroll
            for (int l = 0; l < LNUM; ++l) {
#pragma unroll
                for (int w = 0; w < NQ; ++w) {
                    const int base = (((f * LNUM) + l) * NQ + w) * 8;
                    const float4 uA = *(const float4*)&gs[base];      // U00, U01
                    const float4 uB = *(const float4*)&gs[base + 4];  // U10, U11
                    const int m = 32 >> w;
                    const float br = __shfl_xor(ar, m);
                    const float bi = __shfl_xor(ai, m);
                    const bool hi = (lane & m) != 0;
                    // mine-coeff: hi ? U11 : U00 ; partner-coeff: hi ? U10 : U01
                    const float cmr = hi ? uB.z : uA.x;
                    const float cmi = hi ? uB.w : uA.y;
                    const float cpr = hi ? uB.x : uA.z;
                    const float cpi = hi ? uB.y : uA.w;
                    const float nr = cmr * ar - cmi * ai + cpr * br - cpi * bi;
                    const float ni = cmr * ai + cmi * ar + cpr * bi + cpi * br;
                    ar = nr; ai = ni;
                }
                const int src = l ? src1 : src0;
                ar = __shfl(ar, src);
                ai = __shfl(ai, src);
            }
        }
        // probabilities -> 6 signed wave reductions (Z expectations)
        const float p = ar * ar + ai * ai;
#pragma unroll
        for (int q = 0; q < NQ; ++q) {
            float sv = ((lane >> (5 - q)) & 1) ? -p : p;
#pragma unroll
            for (int m = 32; m >= 1; m >>= 1) sv += __shfl_xor(sv, m);
            if (lane == 0)
                out[((b * (FNUM * NQ) + f * NQ + q) * OH + i) * OH + j] = sv;
        }
    }
}

extern "C" void kernel_launch(void* const* d_in, const int* in_sizes, int n_in,
                              void* d_out, int out_size, void* d_ws, size_t ws_size,
                              hipStream_t stream) {
    const float* x = (const float*)d_in[0];   // (128, 4, 64, 64)
    const float* w = (const float*)d_in[1];   // (4, 2, 6, 3)
    float* out = (float*)d_out;               // (128, 24, 31, 31)
    float* g   = (float*)d_ws;                // 384 floats of gate matrices

    prep_gates<<<1, 64, 0, stream>>>(w, g);

    const int npatch = 128 * OH * OH;         // 123008, divisible by 4
    qconv_kernel<<<npatch / 4, 256, 0, stream>>>(x, g, out);
}

// Round 2
// 57.371 us; speedup vs baseline: 9.6727x; 9.6727x over previous
//
#include <hip/hip_runtime.h>

#define OH 31
#define NPB 64   // patches per block

typedef float f32x4 __attribute__((ext_vector_type(4)));
typedef __bf16 bf16x8 __attribute__((ext_vector_type(8)));

static __device__ __forceinline__ unsigned short f2bf(float v) {
    unsigned u = __builtin_bit_cast(unsigned, v);
    unsigned r = (u + 0x7FFFu + ((u >> 16) & 1u)) >> 16;
    return (unsigned short)r;
}
static __device__ __forceinline__ float bf2f(unsigned short h) {
    unsigned u = ((unsigned)h) << 16;
    return __builtin_bit_cast(float, u);
}
static __device__ __forceinline__ bf16x8 ldg8(const unsigned short* p) {
    uint4 u = *(const uint4*)p;
    return __builtin_bit_cast(bf16x8, u);
}
static __device__ __forceinline__ f32x4 mfma16(bf16x8 a, bf16x8 b, f32x4 c) {
    return __builtin_amdgcn_mfma_f32_16x16x32_bf16(a, b, c, 0, 0, 0);
}

// ---------------------------------------------------------------------------
// prep_M: simulate the 64 basis states for each f -> M_f (64x64 complex),
// stored as bf16 hi/lo arrays laid out [f][re/im][row d][k].
// Grid: 64 blocks x 256 threads; block handles f = blockIdx>>4, 4 basis states.
// ---------------------------------------------------------------------------
__global__ __launch_bounds__(256) void prep_M(const float* __restrict__ wts,
                                              unsigned short* __restrict__ Mhi,
                                              unsigned short* __restrict__ Mlo) {
    __shared__ float gls[12][8];
    const int f = blockIdx.x >> 4;
    const int tid = threadIdx.x;
    if (tid < 12) {
        int l = tid / 6, w = tid % 6;
        const float* p = wts + ((f * 2 + l) * 6 + w) * 3;
        float phi = p[0], theta = p[1], omega = p[2];
        float c, s; sincosf(0.5f * theta, &s, &c);
        float sapo, capo, samo, camo;
        sincosf(0.5f * (phi + omega), &sapo, &capo);
        sincosf(0.5f * (phi - omega), &samo, &camo);
        float* o = gls[tid];
        o[0] =  capo * c;  o[1] = -sapo * c;
        o[2] = -camo * s;  o[3] = -samo * s;
        o[4] =  camo * s;  o[5] = -samo * s;
        o[6] =  capo * c;  o[7] =  sapo * c;
    }
    __syncthreads();

    const int lane = tid & 63;
    const int wid  = tid >> 6;
    const int bas  = (blockIdx.x & 15) * 4 + wid;   // basis index 0..63

    int src0 = lane, src1 = lane;
#pragma unroll
    for (int w = 5; w >= 0; --w) { int tq = (w + 1) % 6; src0 ^= ((src0 >> (5 - w)) & 1) << (5 - tq); }
#pragma unroll
    for (int w = 5; w >= 0; --w) { int tq = (w + 2) % 6; src1 ^= ((src1 >> (5 - w)) & 1) << (5 - tq); }

    float ar = (lane == bas) ? 1.0f : 0.0f, ai = 0.0f;
#pragma unroll
    for (int rep = 0; rep < 2; ++rep) {
#pragma unroll
        for (int l = 0; l < 2; ++l) {
#pragma unroll
            for (int w = 0; w < 6; ++w) {
                const float* gp = gls[l * 6 + w];
                const float4 uA = *(const float4*)gp;
                const float4 uB = *(const float4*)(gp + 4);
                const int m = 32 >> w;
                const float br = __shfl_xor(ar, m);
                const float bi = __shfl_xor(ai, m);
                const bool hi = (lane & m) != 0;
                const float cmr = hi ? uB.z : uA.x;
                const float cmi = hi ? uB.w : uA.y;
                const float cpr = hi ? uB.x : uA.z;
                const float cpi = hi ? uB.y : uA.w;
                const float nr = cmr * ar - cmi * ai + cpr * br - cpi * bi;
                const float ni = cmr * ai + cmi * ar + cpr * bi + cpi * br;
                ar = nr; ai = ni;
            }
            const int src = l ? src1 : src0;
            ar = __shfl(ar, src);
            ai = __shfl(ai, src);
        }
    }
    // lane d holds M[d][bas]
    const int o_re = ((f * 2 + 0) * 64 + lane) * 64 + bas;
    const int o_im = ((f * 2 + 1) * 64 + lane) * 64 + bas;
    unsigned short hr = f2bf(ar);
    Mhi[o_re] = hr; Mlo[o_re] = f2bf(ar - bf2f(hr));
    unsigned short hm = f2bf(ai);
    Mhi[o_im] = hm; Mlo[o_im] = f2bf(ai - bf2f(hm));
}

// ---------------------------------------------------------------------------
// Main kernel: 64 patches/block, 4 waves. Wave w owns d-rows 16w..16w+15
// (re and im). MFMA 16x16x32 bf16 with hi/lo split (3-term).
// ---------------------------------------------------------------------------
__global__ __launch_bounds__(256) void qconv_main(
        const float* __restrict__ x,
        const unsigned short* __restrict__ Mhi,
        const unsigned short* __restrict__ Mlo,
        float* __restrict__ out) {
    __shared__ float patT[64][65];            // [patch][k], fp32 staging
    __shared__ unsigned int psiThi[64][44];   // [patch][k pairs], pitch 176B
    __shared__ unsigned int psiTlo[64][44];
    __shared__ float prt[4][64];
    __shared__ float rn[64];
    __shared__ float zbuf[4][6][64];

    const int tid = threadIdx.x;
    const int n0  = blockIdx.x * NPB;

    // ---- load 64 patches (64 elems each) into patT[p][k] ----
    for (int e = tid; e < 4096; e += 256) {
        int k = e >> 6, p = e & 63;
        int n = n0 + p;
        int b = n / 961, pos = n - b * 961;
        int i = pos / 31, j = pos - i * 31;
        int c = k >> 4, kh = (k >> 2) & 3, kw = k & 3;
        patT[p][k] = x[((b * 4 + c) * 64 + (i * 2 + kh)) * 64 + (j * 2 + kw)];
    }
    __syncthreads();

    // ---- norms ----
    {
        int p = tid & 63, quarter = tid >> 6;
        float ss = 0.0f;
#pragma unroll
        for (int kk = 0; kk < 16; ++kk) { float v = patT[p][quarter * 16 + kk]; ss += v * v; }
        prt[quarter][p] = ss;
    }
    __syncthreads();
    if (tid < 64) rn[tid] = rsqrtf(prt[0][tid] + prt[1][tid] + prt[2][tid] + prt[3][tid]);
    __syncthreads();

    // ---- normalize + split to bf16 hi/lo, packed pairs ----
    {
        int p = tid >> 2, kb = (tid & 3) * 16;
        float r = rn[p];
#pragma unroll
        for (int kk = 0; kk < 16; kk += 2) {
            float v0 = patT[p][kb + kk] * r;
            float v1 = patT[p][kb + kk + 1] * r;
            unsigned short h0 = f2bf(v0), h1 = f2bf(v1);
            unsigned short l0 = f2bf(v0 - bf2f(h0)), l1 = f2bf(v1 - bf2f(h1));
            psiThi[p][(kb + kk) >> 1] = (unsigned)h0 | ((unsigned)h1 << 16);
            psiTlo[p][(kb + kk) >> 1] = (unsigned)l0 | ((unsigned)l1 << 16);
        }
    }
    __syncthreads();

    const int lane = tid & 63;
    const int w    = tid >> 6;      // wave id -> d-rowtile
    const int lr   = lane & 15;     // A row / B col / C col
    const int lq   = lane >> 4;     // quad -> k chunk / C row group

#pragma unroll 1
    for (int f = 0; f < 4; ++f) {
        // A fragments from global (L2-resident, 128 KB total)
        const int rebase = ((f * 2 + 0) * 64 + 16 * w + lr) * 64 + lq * 8;
        const int imbase = ((f * 2 + 1) * 64 + 16 * w + lr) * 64 + lq * 8;
        const bf16x8 areh0 = ldg8(Mhi + rebase);
        const bf16x8 areh1 = ldg8(Mhi + rebase + 32);
        const bf16x8 arel0 = ldg8(Mlo + rebase);
        const bf16x8 arel1 = ldg8(Mlo + rebase + 32);
        const bf16x8 aimh0 = ldg8(Mhi + imbase);
        const bf16x8 aimh1 = ldg8(Mhi + imbase + 32);
        const bf16x8 aiml0 = ldg8(Mlo + imbase);
        const bf16x8 aiml1 = ldg8(Mlo + imbase + 32);

        f32x4 cre[4], cim[4];
#pragma unroll
        for (int t = 0; t < 4; ++t) {
            const int prow = t * 16 + lr;
            const bf16x8 bh0 = __builtin_bit_cast(bf16x8, *(const uint4*)&psiThi[prow][lq * 4]);
            const bf16x8 bh1 = __builtin_bit_cast(bf16x8, *(const uint4*)&psiThi[prow][16 + lq * 4]);
            const bf16x8 bl0 = __builtin_bit_cast(bf16x8, *(const uint4*)&psiTlo[prow][lq * 4]);
            const bf16x8 bl1 = __builtin_bit_cast(bf16x8, *(const uint4*)&psiTlo[prow][16 + lq * 4]);
            f32x4 r = {0.f, 0.f, 0.f, 0.f};
            r = mfma16(areh0, bh0, r);
            r = mfma16(areh1, bh1, r);
            r = mfma16(areh0, bl0, r);
            r = mfma16(areh1, bl1, r);
            r = mfma16(arel0, bh0, r);
            r = mfma16(arel1, bh1, r);
            cre[t] = r;
            f32x4 s = {0.f, 0.f, 0.f, 0.f};
            s = mfma16(aimh0, bh0, s);
            s = mfma16(aimh1, bh1, s);
            s = mfma16(aimh0, bl0, s);
            s = mfma16(aimh1, bl1, s);
            s = mfma16(aiml0, bh0, s);
            s = mfma16(aiml1, bh1, s);
            cim[t] = s;
        }

        // probabilities + signed partial sums
#pragma unroll
        for (int t = 0; t < 4; ++t) {
            float zq[6] = {0, 0, 0, 0, 0, 0};
#pragma unroll
            for (int r = 0; r < 4; ++r) {
                float pv = cre[t][r] * cre[t][r] + cim[t][r] * cim[t][r];
                int d = w * 16 + lq * 4 + r;
                zq[0] += (d & 32) ? -pv : pv;
                zq[1] += (d & 16) ? -pv : pv;
                zq[2] += (d & 8)  ? -pv : pv;
                zq[3] += (d & 4)  ? -pv : pv;
                zq[4] += (d & 2)  ? -pv : pv;
                zq[5] += (d & 1)  ? -pv : pv;
            }
#pragma unroll
            for (int q = 0; q < 6; ++q) {
                zq[q] += __shfl_xor(zq[q], 16);
                zq[q] += __shfl_xor(zq[q], 32);
            }
            if (lane < 16) {
#pragma unroll
                for (int q = 0; q < 6; ++q) zbuf[w][q][t * 16 + lane] = zq[q];
            }
        }
        __syncthreads();
        for (int e = tid; e < 384; e += 256) {
            int q = e >> 6, p = e & 63;
            float zv = zbuf[0][q][p] + zbuf[1][q][p] + zbuf[2][q][p] + zbuf[3][q][p];
            int n = n0 + p;
            int b = n / 961, pos = n - b * 961;
            out[(b * 24 + f * 6 + q) * 961 + pos] = zv;
        }
        __syncthreads();
    }
}

extern "C" void kernel_launch(void* const* d_in, const int* in_sizes, int n_in,
                              void* d_out, int out_size, void* d_ws, size_t ws_size,
                              hipStream_t stream) {
    const float* x   = (const float*)d_in[0];   // (128, 4, 64, 64)
    const float* wts = (const float*)d_in[1];   // (4, 2, 6, 3)
    float* out = (float*)d_out;                 // (128, 24, 31, 31)

    unsigned short* Mhi = (unsigned short*)((char*)d_ws + 2048);
    unsigned short* Mlo = (unsigned short*)((char*)d_ws + 2048 + 65536);

    prep_M<<<64, 256, 0, stream>>>(wts, Mhi, Mlo);

    const int npatch = 128 * OH * OH;           // 123008 = 1922 * 64
    qconv_main<<<npatch / NPB, 256, 0, stream>>>(x, Mhi, Mlo, out);
}